// Round 2
// baseline (419.419 us; speedup 1.0000x reference)
//
#include <hip/hip_runtime.h>
#include <math.h>

#define NUM_LAYERS 3
#define KCB 2048        // codebook size
#define DIM 256         // embed dim
#define NROWS 32768     // B*T
#define NQ (NROWS * DIM)

// d_ws layout: F = fp16 codebook fragments (16x16x32 layout, unchanged).
//   tile tn (16 cw) = 16384 B = 8 kb-blocks of [hi 1024 B | lo 1024 B]
//   within a 1024 B half: lane*16 B -> 8 halves: W[tn*16+(lane&15)][kb*32+(lane>>4)*8+j]
//   layer stride 2 MB. wsq (fp32 ||w||^2, 3*2048) at byte offset F_BYTES.
//   chunk c = 32 KB = tiles {2c, 2c+1} at Fb + c*32768.
#define F_BYTES (3u * 128u * 16384u)   // 6,291,456

// dynamic LDS partition (bytes) -- 67,072 B/block so 2 blocks fit per CU
#define BSH_OFF  0        // 2 bufs x 32768 (one 32-cw chunk each)
#define BV_OFF   65536    // 4 waves x 32 rows f32 = 512
#define BI_OFF   66048    // 4 x 32 i32 = 512
#define BIDX_OFF 66560    // 64 i32 = 256
#define RSQ_OFF  66816    // 64 rows f32 = 256
#define SMEM_BYTES 67072

typedef _Float16 half8 __attribute__((ext_vector_type(8)));
typedef float   f32x4 __attribute__((ext_vector_type(4)));

// ---------------- prep: ||w||^2 (unchanged, verified) ----------------
__global__ void rvq_wsq(const float* __restrict__ cb, float* __restrict__ wsq)
{
    int tid = blockIdx.x * 256 + threadIdx.x;   // 0 .. 6143
    const float* p = cb + (size_t)tid * DIM;
    float s = 0.f;
    #pragma unroll
    for (int u = 0; u < 64; ++u) {
        float4 v = *(const float4*)(p + u * 4);
        s = fmaf(v.x, v.x, s); s = fmaf(v.y, v.y, s);
        s = fmaf(v.z, v.z, s); s = fmaf(v.w, v.w, s);
    }
    wsq[tid] = s;
}

// ---------------- prep: fp16 hi/lo fragment repack (unchanged, verified) ----------------
__global__ void rvq_repack(const float* __restrict__ cb, unsigned short* __restrict__ F)
{
    int b = blockIdx.x;           // layer*1024 + tn*8 + kb
    int layer = b >> 10;
    int rem   = b & 1023;
    int tn    = rem >> 3;
    int kb    = rem & 7;
    int lane  = threadIdx.x;

    int cw = tn * 16 + (lane & 15);
    int k0 = kb * 32 + (lane >> 4) * 8;
    const float* src = cb + ((size_t)(layer * KCB + cw)) * DIM + k0;
    float4 x0 = *(const float4*)(src);
    float4 x1 = *(const float4*)(src + 4);
    float v[8] = {x0.x, x0.y, x0.z, x0.w, x1.x, x1.y, x1.z, x1.w};

    half8 hi, lo;
    #pragma unroll
    for (int j = 0; j < 8; ++j) {
        _Float16 h = (_Float16)v[j];
        hi[j] = h;
        lo[j] = (_Float16)(v[j] - (float)h);
    }
    size_t base = ((size_t)b) * 1024;   // ushort units (2048 B per (layer,tn,kb))
    *(half8*)(F + base + lane * 8)        = hi;
    *(half8*)(F + base + 512 + lane * 8)  = lo;
}

// ---------------- async stage of one 32 KB chunk (256 threads) ----------------
__device__ __forceinline__ void stage_chunk32(const char* Fb, char* dst, int c, int t)
{
    const char* g = Fb + (size_t)c * 32768;
    #pragma unroll
    for (int i = 0; i < 8; ++i) {
        int off = (i * 256 + t) * 16;
        __builtin_amdgcn_global_load_lds(
            (const __attribute__((address_space(1))) unsigned int*)(g + off),
            (__attribute__((address_space(3))) unsigned int*)(dst + off), 16, 0, 0);
    }
}

// ---------------- full cross for one 16-cw tile over full K ----------------
// B-fragments software-pipelined 1 kb ahead in registers; 4-accumulator
// rotation keeps dependent MFMAs on the same acc >= 4 issue slots apart.
__device__ __forceinline__ void tile_full(
    const char* tbase, const half8 (&ahi)[2][8], const half8 (&alo)[2][8],
    int lane, f32x4 (&po)[2])
{
    const f32x4 z = {0.f, 0.f, 0.f, 0.f};
    f32x4 a00 = z, a01 = z, a10 = z, a11 = z;
    const char* p = tbase + lane * 16;
    half8 bhi = *(const half8*)(p);
    half8 blo = *(const half8*)(p + 1024);
    #pragma unroll
    for (int kb = 0; kb < 8; ++kb) {
        half8 nhi, nlo;
        if (kb < 7) {
            nhi = *(const half8*)(p + (kb + 1) * 2048);
            nlo = *(const half8*)(p + (kb + 1) * 2048 + 1024);
        }
        if (kb & 1) {
            a01 = __builtin_amdgcn_mfma_f32_16x16x32_f16(ahi[0][kb], bhi, a01, 0, 0, 0);
            a11 = __builtin_amdgcn_mfma_f32_16x16x32_f16(ahi[1][kb], bhi, a11, 0, 0, 0);
            a00 = __builtin_amdgcn_mfma_f32_16x16x32_f16(alo[0][kb], bhi, a00, 0, 0, 0);
            a10 = __builtin_amdgcn_mfma_f32_16x16x32_f16(alo[1][kb], bhi, a10, 0, 0, 0);
            a01 = __builtin_amdgcn_mfma_f32_16x16x32_f16(ahi[0][kb], blo, a01, 0, 0, 0);
            a11 = __builtin_amdgcn_mfma_f32_16x16x32_f16(ahi[1][kb], blo, a11, 0, 0, 0);
        } else {
            a00 = __builtin_amdgcn_mfma_f32_16x16x32_f16(ahi[0][kb], bhi, a00, 0, 0, 0);
            a10 = __builtin_amdgcn_mfma_f32_16x16x32_f16(ahi[1][kb], bhi, a10, 0, 0, 0);
            a01 = __builtin_amdgcn_mfma_f32_16x16x32_f16(alo[0][kb], bhi, a01, 0, 0, 0);
            a11 = __builtin_amdgcn_mfma_f32_16x16x32_f16(alo[1][kb], bhi, a11, 0, 0, 0);
            a00 = __builtin_amdgcn_mfma_f32_16x16x32_f16(ahi[0][kb], blo, a00, 0, 0, 0);
            a10 = __builtin_amdgcn_mfma_f32_16x16x32_f16(ahi[1][kb], blo, a10, 0, 0, 0);
        }
        if (kb < 7) { bhi = nhi; blo = nlo; }
    }
    #pragma unroll
    for (int i = 0; i < 4; ++i) { po[0][i] = a00[i] + a01[i]; po[1][i] = a10[i] + a11[i]; }
}

// ---------------- main fused RVQ ----------------
// 256 thr = 4 waves: wave = rg(0..1)*2 + ct(0..1). 64 rows/block, grid 512
// (2 independent blocks/CU -> desynced barriers overlap MFMA and LDS pipes).
// Each wave holds full-K residual hi/lo fragments (128 VGPRs) and computes the
// complete cross for its own 16-cw tile: no per-chunk partial exchange.
// waves_per_eu(2,2): pin allocator to the 256-VGPR/wave budget this needs
// (launch_bounds(256,2) let it target 128 regs -> 214 MB of spill traffic, R1).
__global__ __attribute__((amdgpu_flat_work_group_size(256, 256), amdgpu_waves_per_eu(2, 2)))
void rvq_main(const float* __restrict__ h,
              const float* __restrict__ cb,
              const unsigned short* __restrict__ F,
              const float* __restrict__ wsq,
              float* __restrict__ out)
{
    extern __shared__ char smem[];
    char*  Bsh     = smem + BSH_OFF;
    float* bV_sh   = (float*)(smem + BV_OFF);
    int*   bI_sh   = (int*)  (smem + BI_OFF);
    int*   bidx_sh = (int*)  (smem + BIDX_OFF);
    float* rsq_sh  = (float*)(smem + RSQ_OFF);

    const int t     = threadIdx.x;
    const int lane  = t & 63;
    const int wv    = t >> 6;         // 0..3
    const int ct    = wv & 1;         // codeword-tile team: tile (2c+ct) of chunk c
    const int rg    = wv >> 1;        // row group (32 rows each)
    const int rowB  = blockIdx.x * 64;
    const int row0w = rowB + rg * 32;
    const int arow  = lane & 15;      // A row / C col
    const int aq    = lane >> 4;      // k-quad / C row-quad

    // ---- residual fragments (fp16 hi/lo, full K) + ||r||^2 partials ----
    half8 ahi[2][8], alo[2][8];
    float s2[2];
    #pragma unroll
    for (int mi = 0; mi < 2; ++mi) {
        s2[mi] = 0.f;
        #pragma unroll
        for (int kb = 0; kb < 8; ++kb) {
            const float* p = h + (size_t)(row0w + mi * 16 + arow) * DIM + kb * 32 + aq * 8;
            float4 x0 = *(const float4*)(p);
            float4 x1 = *(const float4*)(p + 4);
            float v[8] = {x0.x, x0.y, x0.z, x0.w, x1.x, x1.y, x1.z, x1.w};
            #pragma unroll
            for (int j = 0; j < 8; ++j) {
                _Float16 hv = (_Float16)v[j];
                ahi[mi][kb][j] = hv;
                alo[mi][kb][j] = (_Float16)(v[j] - (float)hv);
                s2[mi] = fmaf(v[j], v[j], s2[mi]);
            }
        }
    }

    // ---- prefetch layer 0, chunk 0 into buf 0 ----
    stage_chunk32((const char*)F, Bsh, 0, t);

    for (int l = 0; l < NUM_LAYERS; ++l) {
        const float* __restrict__ Wl  = cb + (size_t)l * KCB * DIM;
        const float* __restrict__ wql = wsq + l * KCB;
        const char*  Fb = (const char*)F + (size_t)l * 2097152;

        // ---- per-row ||r||^2: reduce across aq lanes, publish once ----
        float a0 = s2[0], a1 = s2[1];
        a0 += __shfl_xor(a0, 16); a0 += __shfl_xor(a0, 32);
        a1 += __shfl_xor(a1, 16); a1 += __shfl_xor(a1, 32);
        if (aq == 0 && ct == 0) {
            rsq_sh[rg * 32 + arow]      = a0;
            rsq_sh[rg * 32 + 16 + arow] = a1;
        }
        __syncthreads();   // rsq visible; chunk-0 staging drained

        float rsqC[2][4];
        #pragma unroll
        for (int mi = 0; mi < 2; ++mi)
            #pragma unroll
            for (int i = 0; i < 4; ++i)
                rsqC[mi][i] = rsq_sh[rg * 32 + mi * 16 + aq * 4 + i];

        float bestV[2][4];
        int   bestI[2][4];
        #pragma unroll
        for (int mi = 0; mi < 2; ++mi)
            #pragma unroll
            for (int i = 0; i < 4; ++i) { bestV[mi][i] = INFINITY; bestI[mi][i] = 0; }

        // ---- 64 chunks of 32 cw; wave handles tile (2c+ct); 1 barrier/chunk ----
        for (int c = 0; c < 64; ++c) {
            const int cur = c & 1;
            if (c + 1 < 64) stage_chunk32(Fb, Bsh + (size_t)(1 - cur) * 32768, c + 1, t);

            f32x4 po[2];
            tile_full(Bsh + (size_t)cur * 32768 + (size_t)ct * 16384, ahi, alo, lane, po);

            const int col = c * 32 + ct * 16 + arow;
            const float wq = wql[col];
            #pragma unroll
            for (int i = 0; i < 4; ++i) {
                float d0 = (rsqC[0][i] - 2.f * po[0][i]) + wq;
                if (d0 < bestV[0][i]) { bestV[0][i] = d0; bestI[0][i] = col; }
                float d1 = (rsqC[1][i] - 2.f * po[1][i]) + wq;
                if (d1 < bestV[1][i]) { bestV[1][i] = d1; bestI[1][i] = col; }
            }
            __syncthreads();   // all reads of buf cur done; next-chunk staging drained
        }

        // ---- argmin: reduce across the 16 arow-lanes sharing each row-quad ----
        #pragma unroll
        for (int mi = 0; mi < 2; ++mi)
            #pragma unroll
            for (int i = 0; i < 4; ++i) {
                float bv = bestV[mi][i]; int bi = bestI[mi][i];
                #pragma unroll
                for (int s = 8; s; s >>= 1) {
                    float ov = __shfl_xor(bv, s, 16);
                    int   oi = __shfl_xor(bi, s, 16);
                    if (ov < bv || (ov == bv && oi < bi)) { bv = ov; bi = oi; }
                }
                bestV[mi][i] = bv; bestI[mi][i] = bi;
            }
        if (arow == 0) {
            #pragma unroll
            for (int mi = 0; mi < 2; ++mi)
                #pragma unroll
                for (int i = 0; i < 4; ++i) {
                    bV_sh[wv * 32 + mi * 16 + aq * 4 + i] = bestV[mi][i];
                    bI_sh[wv * 32 + mi * 16 + aq * 4 + i] = bestI[mi][i];
                }
        }
        __syncthreads();

        // ---- combine the two ct-teams' col-halves per row, write index ----
        if (t < 64) {
            int rgi = t >> 5, rl = t & 31;
            float v0 = bV_sh[(rgi * 2 + 0) * 32 + rl]; int i0 = bI_sh[(rgi * 2 + 0) * 32 + rl];
            float v1 = bV_sh[(rgi * 2 + 1) * 32 + rl]; int i1 = bI_sh[(rgi * 2 + 1) * 32 + rl];
            int bi = (v1 < v0 || (v1 == v0 && i1 < i0)) ? i1 : i0;
            bidx_sh[t] = bi;
            out[NQ + (size_t)l * NROWS + rowB + t] = (float)bi;
        }
        // prefetch next layer's chunk 0 (independent of bidx) into buf 0
        if (l < NUM_LAYERS - 1)
            stage_chunk32(Fb + 2097152, Bsh, 0, t);
        __syncthreads();   // bidx_sh visible

        if (l < NUM_LAYERS - 1) {
            // ---- residual update in registers: r <- (hi+lo) - w, re-split ----
            // (duplicated across ct teams: both need the full-K fragments)
            #pragma unroll
            for (int mi = 0; mi < 2; ++mi) {
                const int bi = bidx_sh[rg * 32 + mi * 16 + arow];
                const float* wrow = Wl + (size_t)bi * DIM;
                float ns = 0.f;
                #pragma unroll
                for (int kb = 0; kb < 8; ++kb) {
                    const float* wp = wrow + kb * 32 + aq * 8;
                    float4 w0 = *(const float4*)(wp);
                    float4 w1 = *(const float4*)(wp + 4);
                    float wv8[8] = {w0.x, w0.y, w0.z, w0.w, w1.x, w1.y, w1.z, w1.w};
                    #pragma unroll
                    for (int j = 0; j < 8; ++j) {
                        float r = ((float)ahi[mi][kb][j] + (float)alo[mi][kb][j]) - wv8[j];
                        _Float16 hv = (_Float16)r;
                        ahi[mi][kb][j] = hv;
                        alo[mi][kb][j] = (_Float16)(r - (float)hv);
                        ns = fmaf(r, r, ns);
                    }
                }
                s2[mi] = ns;
            }
        } else {
            // ---- final: out = h - (r2 - w3); ct teams split the k-range ----
            #pragma unroll
            for (int mi = 0; mi < 2; ++mi) {
                const int row = row0w + mi * 16 + arow;
                const int bi  = bidx_sh[rg * 32 + mi * 16 + arow];
                const float* wrow = Wl + (size_t)bi * DIM;
                #pragma unroll
                for (int kq = 0; kq < 4; ++kq) {
                    const int kb = ct * 4 + kq;
                    const int ko = kb * 32 + aq * 8;
                    const float* wp = wrow + ko;
                    const float* hp = h + (size_t)row * DIM + ko;
                    float4 w0 = *(const float4*)(wp);
                    float4 w1 = *(const float4*)(wp + 4);
                    float4 h0 = *(const float4*)(hp);
                    float4 h1 = *(const float4*)(hp + 4);
                    float wv8[8] = {w0.x, w0.y, w0.z, w0.w, w1.x, w1.y, w1.z, w1.w};
                    float hv8[8] = {h0.x, h0.y, h0.z, h0.w, h1.x, h1.y, h1.z, h1.w};
                    float o[8];
                    #pragma unroll
                    for (int j = 0; j < 8; ++j) {
                        float r = ((float)ahi[mi][kb][j] + (float)alo[mi][kb][j]) - wv8[j];
                        o[j] = hv8[j] - r;
                    }
                    float* op = out + (size_t)row * DIM + ko;
                    *(float4*)(op)     = make_float4(o[0], o[1], o[2], o[3]);
                    *(float4*)(op + 4) = make_float4(o[4], o[5], o[6], o[7]);
                }
            }
        }
    }
}

extern "C" void kernel_launch(void* const* d_in, const int* in_sizes, int n_in,
                              void* d_out, int out_size, void* d_ws, size_t ws_size,
                              hipStream_t stream) {
    const float* h  = (const float*)d_in[0];
    const float* cb = (const float*)d_in[1];
    float* out = (float*)d_out;
    unsigned short* F = (unsigned short*)d_ws;
    float* wsq = (float*)((char*)d_ws + F_BYTES);

    hipFuncSetAttribute((const void*)rvq_main,
                        hipFuncAttributeMaxDynamicSharedMemorySize, SMEM_BYTES);

    rvq_wsq   <<<dim3(24),   dim3(256), 0, stream>>>(cb, wsq);
    rvq_repack<<<dim3(3072), dim3(64),  0, stream>>>(cb, F);
    rvq_main  <<<dim3(NROWS / 64), dim3(256), SMEM_BYTES, stream>>>(h, cb, F, wsq, out);
}

// Round 3
// 415.097 us; speedup vs baseline: 1.0104x; 1.0104x over previous
//
#include <hip/hip_runtime.h>
#include <math.h>

#define NUM_LAYERS 3
#define KCB 2048        // codebook size
#define DIM 256         // embed dim
#define NROWS 32768     // B*T
#define NQ (NROWS * DIM)

// d_ws layout: F = fp16 codebook fragments (16x16x32 layout, verified).
//   tile tn (16 cw) = 16384 B = 8 kb-blocks of [hi 1024 B | lo 1024 B]
//   within a 1024 B half: lane*16 B -> 8 halves: W[tn*16+(lane&15)][kb*32+(lane>>4)*8+j]
//   layer stride 2 MB. wsq (fp32 ||w||^2, 3*2048) at byte offset F_BYTES.
//   chunk c = 32 KB = tiles {2c, 2c+1} at Fb + c*32768.
#define F_BYTES (3u * 128u * 16384u)   // 6,291,456

// dynamic LDS partition (bytes) -- 75,520 B/block so 2 blocks/CU (151 KB of 160 KB)
#define BSH_OFF  0        // 2 bufs x 32768 (one 32-cw chunk each)
#define XCH_OFF  65536    // single buf: [rg 0..1][kt 0..1] x 2048 B = 8192
#define RSQP_OFF 73728    // [kt 0..1][64 rows] f32 = 512
#define BV_OFF   74240    // 4 waves x 32 rows f32 = 512
#define BI_OFF   74752    // 4 x 32 i32 = 512
#define BIDX_OFF 75264    // 64 i32 = 256
#define SMEM_BYTES 75520

typedef _Float16 half8 __attribute__((ext_vector_type(8)));
typedef float   f32x4 __attribute__((ext_vector_type(4)));

// ---------------- prep: ||w||^2 (unchanged, verified) ----------------
__global__ void rvq_wsq(const float* __restrict__ cb, float* __restrict__ wsq)
{
    int tid = blockIdx.x * 256 + threadIdx.x;   // 0 .. 6143
    const float* p = cb + (size_t)tid * DIM;
    float s = 0.f;
    #pragma unroll
    for (int u = 0; u < 64; ++u) {
        float4 v = *(const float4*)(p + u * 4);
        s = fmaf(v.x, v.x, s); s = fmaf(v.y, v.y, s);
        s = fmaf(v.z, v.z, s); s = fmaf(v.w, v.w, s);
    }
    wsq[tid] = s;
}

// ---------------- prep: fp16 hi/lo fragment repack (unchanged, verified) ----------------
__global__ void rvq_repack(const float* __restrict__ cb, unsigned short* __restrict__ F)
{
    int b = blockIdx.x;           // layer*1024 + tn*8 + kb
    int layer = b >> 10;
    int rem   = b & 1023;
    int tn    = rem >> 3;
    int kb    = rem & 7;
    int lane  = threadIdx.x;

    int cw = tn * 16 + (lane & 15);
    int k0 = kb * 32 + (lane >> 4) * 8;
    const float* src = cb + ((size_t)(layer * KCB + cw)) * DIM + k0;
    float4 x0 = *(const float4*)(src);
    float4 x1 = *(const float4*)(src + 4);
    float v[8] = {x0.x, x0.y, x0.z, x0.w, x1.x, x1.y, x1.z, x1.w};

    half8 hi, lo;
    #pragma unroll
    for (int j = 0; j < 8; ++j) {
        _Float16 h = (_Float16)v[j];
        hi[j] = h;
        lo[j] = (_Float16)(v[j] - (float)h);
    }
    size_t base = ((size_t)b) * 1024;   // ushort units (2048 B per (layer,tn,kb))
    *(half8*)(F + base + lane * 8)        = hi;
    *(half8*)(F + base + 512 + lane * 8)  = lo;
}

// ---------------- async stage of one 32 KB chunk (256 threads) ----------------
__device__ __forceinline__ void stage_chunk32(const char* Fb, char* dst, int c, int t)
{
    const char* g = Fb + (size_t)c * 32768;
    #pragma unroll
    for (int i = 0; i < 8; ++i) {
        int off = (i * 256 + t) * 16;
        __builtin_amdgcn_global_load_lds(
            (const __attribute__((address_space(1))) unsigned int*)(g + off),
            (__attribute__((address_space(3))) unsigned int*)(dst + off), 16, 0, 0);
    }
}

// ---------------- partial cross for one 16-cw tile over this wave's k-half ----------------
// (R0-verified structure: 4-acc rotation, JIT LDS loads - compiler hoists/schedules)
__device__ __forceinline__ void tile_partial(
    const char* tbase, const half8 (&ahi)[2][4], const half8 (&alo)[2][4],
    int kt, int lane, f32x4 (&po)[2])
{
    const f32x4 z = {0.f, 0.f, 0.f, 0.f};
    f32x4 a00 = z, a01 = z, a10 = z, a11 = z;
    #pragma unroll
    for (int kq = 0; kq < 4; ++kq) {
        const int kb = kt * 4 + kq;
        half8 bhi = *(const half8*)(tbase + kb * 2048 + lane * 16);
        half8 blo = *(const half8*)(tbase + kb * 2048 + 1024 + lane * 16);
        if (kq & 1) {
            a01 = __builtin_amdgcn_mfma_f32_16x16x32_f16(ahi[0][kq], bhi, a01, 0, 0, 0);
            a11 = __builtin_amdgcn_mfma_f32_16x16x32_f16(ahi[1][kq], bhi, a11, 0, 0, 0);
            a01 = __builtin_amdgcn_mfma_f32_16x16x32_f16(alo[0][kq], bhi, a01, 0, 0, 0);
            a11 = __builtin_amdgcn_mfma_f32_16x16x32_f16(alo[1][kq], bhi, a11, 0, 0, 0);
            a01 = __builtin_amdgcn_mfma_f32_16x16x32_f16(ahi[0][kq], blo, a01, 0, 0, 0);
            a11 = __builtin_amdgcn_mfma_f32_16x16x32_f16(ahi[1][kq], blo, a11, 0, 0, 0);
        } else {
            a00 = __builtin_amdgcn_mfma_f32_16x16x32_f16(ahi[0][kq], bhi, a00, 0, 0, 0);
            a10 = __builtin_amdgcn_mfma_f32_16x16x32_f16(ahi[1][kq], bhi, a10, 0, 0, 0);
            a00 = __builtin_amdgcn_mfma_f32_16x16x32_f16(alo[0][kq], bhi, a00, 0, 0, 0);
            a10 = __builtin_amdgcn_mfma_f32_16x16x32_f16(alo[1][kq], bhi, a10, 0, 0, 0);
            a00 = __builtin_amdgcn_mfma_f32_16x16x32_f16(ahi[0][kq], blo, a00, 0, 0, 0);
            a10 = __builtin_amdgcn_mfma_f32_16x16x32_f16(ahi[1][kq], blo, a10, 0, 0, 0);
        }
    }
    #pragma unroll
    for (int i = 0; i < 4; ++i) { po[0][i] = a00[i] + a01[i]; po[1][i] = a10[i] + a11[i]; }
}

// ---------------- main fused RVQ ----------------
// 256 thr = 4 waves: wave = rg(0..1)*2 + kt(0..1). 64 rows/block, grid 512 ->
// 2 INDEPENDENT blocks/CU: desynced barrier domains overlap one block's MFMA
// phase with the other's LDS/staging-drain phase (R0's 512-thr single block
// ran them serially: 4013 cyc/chunk vs 1862 MFMA + 2176 LDS).
// Each wave holds k-half residual hi/lo fragments (64 VGPRs - proven no-spill
// footprint from R0; full-K = 128 frag regs spilled 216 MB in R1/R2).
// Single Xch buffer + 2 barriers/chunk (LDS budget for 2 blocks/CU).
__global__ __launch_bounds__(256, 2)
void rvq_main(const float* __restrict__ h,
              const float* __restrict__ cb,
              const unsigned short* __restrict__ F,
              const float* __restrict__ wsq,
              float* __restrict__ out)
{
    extern __shared__ char smem[];
    char*  Bsh     = smem + BSH_OFF;
    char*  Xch     = smem + XCH_OFF;
    float* rsqp    = (float*)(smem + RSQP_OFF);
    float* bV_sh   = (float*)(smem + BV_OFF);
    int*   bI_sh   = (int*)  (smem + BI_OFF);
    int*   bidx_sh = (int*)  (smem + BIDX_OFF);

    const int t     = threadIdx.x;
    const int lane  = t & 63;
    const int wv    = t >> 6;         // 0..3
    const int kt    = wv & 1;         // k-team: k in [kt*128, kt*128+128)
    const int rg    = wv >> 1;        // row group (32 rows each)
    const int rowB  = blockIdx.x * 64;
    const int row0w = rowB + rg * 32;
    const int arow  = lane & 15;      // A row / C col
    const int aq    = lane >> 4;      // k-quad / C row-quad

    // ---- residual fragments (fp16 hi/lo, k-half only) + partial ||r||^2 ----
    half8 ahi[2][4], alo[2][4];
    float s2[2];
    #pragma unroll
    for (int mi = 0; mi < 2; ++mi) {
        s2[mi] = 0.f;
        #pragma unroll
        for (int kq = 0; kq < 4; ++kq) {
            const float* p = h + (size_t)(row0w + mi * 16 + arow) * DIM + (kt * 4 + kq) * 32 + aq * 8;
            float4 x0 = *(const float4*)(p);
            float4 x1 = *(const float4*)(p + 4);
            float v[8] = {x0.x, x0.y, x0.z, x0.w, x1.x, x1.y, x1.z, x1.w};
            #pragma unroll
            for (int j = 0; j < 8; ++j) {
                _Float16 hv = (_Float16)v[j];
                ahi[mi][kq][j] = hv;
                alo[mi][kq][j] = (_Float16)(v[j] - (float)hv);
                s2[mi] = fmaf(v[j], v[j], s2[mi]);
            }
        }
    }

    // ---- prefetch layer 0, chunk 0 into buf 0 ----
    stage_chunk32((const char*)F, Bsh, 0, t);

    for (int l = 0; l < NUM_LAYERS; ++l) {
        const float* __restrict__ Wl  = cb + (size_t)l * KCB * DIM;
        const float* __restrict__ wql = wsq + l * KCB;
        const char*  Fb = (const char*)F + (size_t)l * 2097152;

        // ---- per-row ||r||^2: sum over aq in-wave, publish k-half partials ----
        float a0 = s2[0], a1 = s2[1];
        a0 += __shfl_xor(a0, 16); a0 += __shfl_xor(a0, 32);
        a1 += __shfl_xor(a1, 16); a1 += __shfl_xor(a1, 32);
        if (aq == 0) {
            rsqp[kt * 64 + rg * 32 + arow]      = a0;
            rsqp[kt * 64 + rg * 32 + 16 + arow] = a1;
        }
        __syncthreads();   // rsqp visible; chunk-0 staging drained

        float rsqC[2][4];
        #pragma unroll
        for (int mi = 0; mi < 2; ++mi)
            #pragma unroll
            for (int i = 0; i < 4; ++i) {
                int row = rg * 32 + mi * 16 + aq * 4 + i;
                rsqC[mi][i] = rsqp[row] + rsqp[64 + row];
            }

        float bestV[2][4];
        int   bestI[2][4];
        #pragma unroll
        for (int mi = 0; mi < 2; ++mi)
            #pragma unroll
            for (int i = 0; i < 4; ++i) { bestV[mi][i] = INFINITY; bestI[mi][i] = 0; }

        // ---- 64 chunks of 32 cw (tiles 2c, 2c+1), 2 barriers per chunk ----
        for (int c = 0; c < 64; ++c) {
            const int cur = c & 1;
            if (c + 1 < 64) stage_chunk32(Fb, Bsh + (size_t)(1 - cur) * 32768, c + 1, t);
            const char* bb = Bsh + (size_t)cur * 32768;

            __builtin_amdgcn_s_setprio(1);
            // non-owned tile (ti = 1-kt): partials -> LDS
            {
                f32x4 pn[2];
                tile_partial(bb + (size_t)(1 - kt) * 16384, ahi, alo, kt, lane, pn);
                char* xw = Xch + rg * 4096 + kt * 2048;
                *(f32x4*)(xw + lane * 16)        = pn[0];
                *(f32x4*)(xw + 1024 + lane * 16) = pn[1];
            }
            // owned tile (ti = kt): keep partials in regs
            f32x4 po[2];
            tile_partial(bb + (size_t)kt * 16384, ahi, alo, kt, lane, po);
            __builtin_amdgcn_s_setprio(0);

            __syncthreads();   // A: exchange visible; next-chunk staging drained

            const char* xr = Xch + rg * 4096 + (1 - kt) * 2048;
            f32x4 pp0 = *(const f32x4*)(xr + lane * 16);
            f32x4 pp1 = *(const f32x4*)(xr + 1024 + lane * 16);

            const int col = c * 32 + kt * 16 + arow;
            const float wq = wql[col];
            #pragma unroll
            for (int i = 0; i < 4; ++i) {
                float c0 = po[0][i] + pp0[i];
                float d0 = (rsqC[0][i] - 2.f * c0) + wq;
                if (d0 < bestV[0][i]) { bestV[0][i] = d0; bestI[0][i] = col; }
                float c1 = po[1][i] + pp1[i];
                float d1 = (rsqC[1][i] - 2.f * c1) + wq;
                if (d1 < bestV[1][i]) { bestV[1][i] = d1; bestI[1][i] = col; }
            }
            __syncthreads();   // B: Xch reads done -> next chunk may overwrite
        }

        // ---- argmin: reduce across the 16 arow-lanes sharing each row-quad ----
        #pragma unroll
        for (int mi = 0; mi < 2; ++mi)
            #pragma unroll
            for (int i = 0; i < 4; ++i) {
                float bv = bestV[mi][i]; int bi = bestI[mi][i];
                #pragma unroll
                for (int s = 8; s; s >>= 1) {
                    float ov = __shfl_xor(bv, s, 16);
                    int   oi = __shfl_xor(bi, s, 16);
                    if (ov < bv || (ov == bv && oi < bi)) { bv = ov; bi = oi; }
                }
                bestV[mi][i] = bv; bestI[mi][i] = bi;
            }
        if (arow == 0) {
            #pragma unroll
            for (int mi = 0; mi < 2; ++mi)
                #pragma unroll
                for (int i = 0; i < 4; ++i) {
                    bV_sh[wv * 32 + mi * 16 + aq * 4 + i] = bestV[mi][i];
                    bI_sh[wv * 32 + mi * 16 + aq * 4 + i] = bestI[mi][i];
                }
        }
        __syncthreads();

        // ---- combine the two k-teams' col-halves per row, write index ----
        if (t < 64) {
            int rgi = t >> 5, rl = t & 31;
            float v0 = bV_sh[(rgi * 2 + 0) * 32 + rl]; int i0 = bI_sh[(rgi * 2 + 0) * 32 + rl];
            float v1 = bV_sh[(rgi * 2 + 1) * 32 + rl]; int i1 = bI_sh[(rgi * 2 + 1) * 32 + rl];
            int bi = (v1 < v0 || (v1 == v0 && i1 < i0)) ? i1 : i0;
            bidx_sh[t] = bi;
            out[NQ + (size_t)l * NROWS + rowB + t] = (float)bi;
        }
        // prefetch next layer's chunk 0 (independent of bidx) into buf 0
        if (l < NUM_LAYERS - 1)
            stage_chunk32(Fb + 2097152, Bsh, 0, t);
        __syncthreads();   // bidx_sh visible

        if (l < NUM_LAYERS - 1) {
            // ---- residual update in registers: r <- (hi+lo) - w, re-split ----
            #pragma unroll
            for (int mi = 0; mi < 2; ++mi) {
                const int bi = bidx_sh[rg * 32 + mi * 16 + arow];
                const float* wrow = Wl + (size_t)bi * DIM;
                float ns = 0.f;
                #pragma unroll
                for (int kq = 0; kq < 4; ++kq) {
                    const float* wp = wrow + (kt * 4 + kq) * 32 + aq * 8;
                    float4 w0 = *(const float4*)(wp);
                    float4 w1 = *(const float4*)(wp + 4);
                    float wv8[8] = {w0.x, w0.y, w0.z, w0.w, w1.x, w1.y, w1.z, w1.w};
                    #pragma unroll
                    for (int j = 0; j < 8; ++j) {
                        float r = ((float)ahi[mi][kq][j] + (float)alo[mi][kq][j]) - wv8[j];
                        _Float16 hv = (_Float16)r;
                        ahi[mi][kq][j] = hv;
                        alo[mi][kq][j] = (_Float16)(r - (float)hv);
                        ns = fmaf(r, r, ns);
                    }
                }
                s2[mi] = ns;
            }
        } else {
            // ---- final: out = h - (r2 - w3); each lane covers its k-half ----
            #pragma unroll
            for (int mi = 0; mi < 2; ++mi) {
                const int row = row0w + mi * 16 + arow;
                const int bi  = bidx_sh[rg * 32 + mi * 16 + arow];
                const float* wrow = Wl + (size_t)bi * DIM;
                #pragma unroll
                for (int kq = 0; kq < 4; ++kq) {
                    const int ko = (kt * 4 + kq) * 32 + aq * 8;
                    const float* wp = wrow + ko;
                    const float* hp = h + (size_t)row * DIM + ko;
                    float4 w0 = *(const float4*)(wp);
                    float4 w1 = *(const float4*)(wp + 4);
                    float4 h0 = *(const float4*)(hp);
                    float4 h1 = *(const float4*)(hp + 4);
                    float wv8[8] = {w0.x, w0.y, w0.z, w0.w, w1.x, w1.y, w1.z, w1.w};
                    float hv8[8] = {h0.x, h0.y, h0.z, h0.w, h1.x, h1.y, h1.z, h1.w};
                    float o[8];
                    #pragma unroll
                    for (int j = 0; j < 8; ++j) {
                        float r = ((float)ahi[mi][kq][j] + (float)alo[mi][kq][j]) - wv8[j];
                        o[j] = hv8[j] - r;
                    }
                    float* op = out + (size_t)row * DIM + ko;
                    *(float4*)(op)     = make_float4(o[0], o[1], o[2], o[3]);
                    *(float4*)(op + 4) = make_float4(o[4], o[5], o[6], o[7]);
                }
            }
        }
    }
}

extern "C" void kernel_launch(void* const* d_in, const int* in_sizes, int n_in,
                              void* d_out, int out_size, void* d_ws, size_t ws_size,
                              hipStream_t stream) {
    const float* h  = (const float*)d_in[0];
    const float* cb = (const float*)d_in[1];
    float* out = (float*)d_out;
    unsigned short* F = (unsigned short*)d_ws;
    float* wsq = (float*)((char*)d_ws + F_BYTES);

    hipFuncSetAttribute((const void*)rvq_main,
                        hipFuncAttributeMaxDynamicSharedMemorySize, SMEM_BYTES);

    rvq_wsq   <<<dim3(24),   dim3(256), 0, stream>>>(cb, wsq);
    rvq_repack<<<dim3(3072), dim3(64),  0, stream>>>(cb, F);
    rvq_main  <<<dim3(NROWS / 64), dim3(256), SMEM_BYTES, stream>>>(h, cb, F, wsq, out);
}

// Round 4
// 398.896 us; speedup vs baseline: 1.0514x; 1.0406x over previous
//
#include <hip/hip_runtime.h>
#include <math.h>

#define NUM_LAYERS 3
#define KCB 2048        // codebook size
#define DIM 256         // embed dim
#define NROWS 32768     // B*T
#define NQ (NROWS * DIM)

// d_ws layout: F = fp16 codebook fragments (16x16x32 layout, verified).
//   tile tn (16 cw) = 16384 B = 8 kb-blocks of [hi 1024 B | lo 1024 B]
//   within a 1024 B half: lane*16 B -> 8 halves: W[tn*16+(lane&15)][kb*32+(lane>>4)*8+j]
//   layer stride 2 MB. wsq (fp32 ||w||^2, 3*2048) at byte offset F_BYTES.
//   chunk c = 32 KB = tiles {2c, 2c+1} at Fb + c*32768.
#define F_BYTES (3u * 128u * 16384u)   // 6,291,456

// dynamic LDS partition (bytes) -- 75,520 B/block so 2 blocks/CU (151 KB of 160 KB)
#define BSH_OFF  0        // 2 bufs x 32768 (one 32-cw chunk each)
#define XCH_OFF  65536    // single buf: [rg 0..1][kt 0..1] x 2048 B = 8192
#define RSQP_OFF 73728    // [kt 0..1][64 rows] f32 = 512
#define BV_OFF   74240    // 4 waves x 32 rows f32 = 512
#define BI_OFF   74752    // 4 x 32 i32 = 512
#define BIDX_OFF 75264    // 64 i32 = 256
#define SMEM_BYTES 75520

typedef _Float16 half8 __attribute__((ext_vector_type(8)));
typedef float   f32x4 __attribute__((ext_vector_type(4)));

// ---------------- prep: ||w||^2 (unchanged, verified) ----------------
__global__ void rvq_wsq(const float* __restrict__ cb, float* __restrict__ wsq)
{
    int tid = blockIdx.x * 256 + threadIdx.x;   // 0 .. 6143
    const float* p = cb + (size_t)tid * DIM;
    float s = 0.f;
    #pragma unroll
    for (int u = 0; u < 64; ++u) {
        float4 v = *(const float4*)(p + u * 4);
        s = fmaf(v.x, v.x, s); s = fmaf(v.y, v.y, s);
        s = fmaf(v.z, v.z, s); s = fmaf(v.w, v.w, s);
    }
    wsq[tid] = s;
}

// ---------------- prep: fp16 hi/lo fragment repack (unchanged, verified) ----------------
__global__ void rvq_repack(const float* __restrict__ cb, unsigned short* __restrict__ F)
{
    int b = blockIdx.x;           // layer*1024 + tn*8 + kb
    int layer = b >> 10;
    int rem   = b & 1023;
    int tn    = rem >> 3;
    int kb    = rem & 7;
    int lane  = threadIdx.x;

    int cw = tn * 16 + (lane & 15);
    int k0 = kb * 32 + (lane >> 4) * 8;
    const float* src = cb + ((size_t)(layer * KCB + cw)) * DIM + k0;
    float4 x0 = *(const float4*)(src);
    float4 x1 = *(const float4*)(src + 4);
    float v[8] = {x0.x, x0.y, x0.z, x0.w, x1.x, x1.y, x1.z, x1.w};

    half8 hi, lo;
    #pragma unroll
    for (int j = 0; j < 8; ++j) {
        _Float16 h = (_Float16)v[j];
        hi[j] = h;
        lo[j] = (_Float16)(v[j] - (float)h);
    }
    size_t base = ((size_t)b) * 1024;   // ushort units (2048 B per (layer,tn,kb))
    *(half8*)(F + base + lane * 8)        = hi;
    *(half8*)(F + base + 512 + lane * 8)  = lo;
}

// ---------------- async stage of one 32 KB chunk (256 threads) ----------------
__device__ __forceinline__ void stage_chunk32(const char* Fb, char* dst, int c, int t)
{
    const char* g = Fb + (size_t)c * 32768;
    #pragma unroll
    for (int i = 0; i < 8; ++i) {
        int off = (i * 256 + t) * 16;
        __builtin_amdgcn_global_load_lds(
            (const __attribute__((address_space(1))) unsigned int*)(g + off),
            (__attribute__((address_space(3))) unsigned int*)(dst + off), 16, 0, 0);
    }
}

// ---------------- pipelined partial cross: 16-cw tile over this wave's k-half ----------------
// 1-step register prefetch (load kq+1 while MFMA-ing kq) + sched_group_barrier
// pins {DS_READ x2, MFMA x6} per step so the emitted schedule interleaves the
// LDS pipe with the matrix pipe (R3 measured ZERO overlap: 4675 cyc/chunk =
// 1862 MFMA + 2566 LDS serial sum).
__device__ __forceinline__ void tile_partial_pl(
    const char* tbase, const half8 (&ahi)[2][4], const half8 (&alo)[2][4],
    int kt, int lane, f32x4 (&po)[2])
{
    const f32x4 z = {0.f, 0.f, 0.f, 0.f};
    f32x4 a00 = z, a01 = z, a10 = z, a11 = z;
    const char* p = tbase + kt * 4 * 2048 + lane * 16;
    half8 bhi = *(const half8*)(p);
    half8 blo = *(const half8*)(p + 1024);
    #pragma unroll
    for (int kq = 0; kq < 4; ++kq) {
        half8 nhi, nlo;
        if (kq < 3) {
            nhi = *(const half8*)(p + (kq + 1) * 2048);
            nlo = *(const half8*)(p + (kq + 1) * 2048 + 1024);
            __builtin_amdgcn_sched_group_barrier(0x100, 2, 0);   // 2 DS_READ
        }
        if (kq & 1) {
            a01 = __builtin_amdgcn_mfma_f32_16x16x32_f16(ahi[0][kq], bhi, a01, 0, 0, 0);
            a11 = __builtin_amdgcn_mfma_f32_16x16x32_f16(ahi[1][kq], bhi, a11, 0, 0, 0);
            a01 = __builtin_amdgcn_mfma_f32_16x16x32_f16(alo[0][kq], bhi, a01, 0, 0, 0);
            a11 = __builtin_amdgcn_mfma_f32_16x16x32_f16(alo[1][kq], bhi, a11, 0, 0, 0);
            a01 = __builtin_amdgcn_mfma_f32_16x16x32_f16(ahi[0][kq], blo, a01, 0, 0, 0);
            a11 = __builtin_amdgcn_mfma_f32_16x16x32_f16(ahi[1][kq], blo, a11, 0, 0, 0);
        } else {
            a00 = __builtin_amdgcn_mfma_f32_16x16x32_f16(ahi[0][kq], bhi, a00, 0, 0, 0);
            a10 = __builtin_amdgcn_mfma_f32_16x16x32_f16(ahi[1][kq], bhi, a10, 0, 0, 0);
            a00 = __builtin_amdgcn_mfma_f32_16x16x32_f16(alo[0][kq], bhi, a00, 0, 0, 0);
            a10 = __builtin_amdgcn_mfma_f32_16x16x32_f16(alo[1][kq], bhi, a10, 0, 0, 0);
            a00 = __builtin_amdgcn_mfma_f32_16x16x32_f16(ahi[0][kq], blo, a00, 0, 0, 0);
            a10 = __builtin_amdgcn_mfma_f32_16x16x32_f16(ahi[1][kq], blo, a10, 0, 0, 0);
        }
        __builtin_amdgcn_sched_group_barrier(0x8, 6, 0);         // 6 MFMA
        if (kq < 3) { bhi = nhi; blo = nlo; }
    }
    #pragma unroll
    for (int i = 0; i < 4; ++i) { po[0][i] = a00[i] + a01[i]; po[1][i] = a10[i] + a11[i]; }
}

// ---------------- main fused RVQ ----------------
// 256 thr = 4 waves: wave = rg(0..1)*2 + kt(0..1). 64 rows/block, grid 512,
// 2 blocks/CU. k-half fragments (64 VGPRs, proven no-spill). Raw s_barrier
// with COUNTED waits: barrier A only drains lgkmcnt (Xch visibility); vmcnt(0)
// deferred to barrier B where the next-chunk staging has had a full chunk to
// land (~free) -- __syncthreads drained vmcnt(0) a chunk early (R0-R3).
__global__ __launch_bounds__(256, 2)
void rvq_main(const float* __restrict__ h,
              const float* __restrict__ cb,
              const unsigned short* __restrict__ F,
              const float* __restrict__ wsq,
              float* __restrict__ out)
{
    extern __shared__ char smem[];
    char*  Bsh     = smem + BSH_OFF;
    char*  Xch     = smem + XCH_OFF;
    float* rsqp    = (float*)(smem + RSQP_OFF);
    float* bV_sh   = (float*)(smem + BV_OFF);
    int*   bI_sh   = (int*)  (smem + BI_OFF);
    int*   bidx_sh = (int*)  (smem + BIDX_OFF);

    const int t     = threadIdx.x;
    const int lane  = t & 63;
    const int wv    = t >> 6;         // 0..3
    const int kt    = wv & 1;         // k-team: k in [kt*128, kt*128+128)
    const int rg    = wv >> 1;        // row group (32 rows each)
    const int rowB  = blockIdx.x * 64;
    const int row0w = rowB + rg * 32;
    const int arow  = lane & 15;      // A row / C col
    const int aq    = lane >> 4;      // k-quad / C row-quad

    // ---- residual fragments (fp16 hi/lo, k-half only) + partial ||r||^2 ----
    half8 ahi[2][4], alo[2][4];
    float s2[2];
    #pragma unroll
    for (int mi = 0; mi < 2; ++mi) {
        s2[mi] = 0.f;
        #pragma unroll
        for (int kq = 0; kq < 4; ++kq) {
            const float* p = h + (size_t)(row0w + mi * 16 + arow) * DIM + (kt * 4 + kq) * 32 + aq * 8;
            float4 x0 = *(const float4*)(p);
            float4 x1 = *(const float4*)(p + 4);
            float v[8] = {x0.x, x0.y, x0.z, x0.w, x1.x, x1.y, x1.z, x1.w};
            #pragma unroll
            for (int j = 0; j < 8; ++j) {
                _Float16 hv = (_Float16)v[j];
                ahi[mi][kq][j] = hv;
                alo[mi][kq][j] = (_Float16)(v[j] - (float)hv);
                s2[mi] = fmaf(v[j], v[j], s2[mi]);
            }
        }
    }

    // ---- prefetch layer 0, chunk 0 into buf 0 ----
    stage_chunk32((const char*)F, Bsh, 0, t);

    for (int l = 0; l < NUM_LAYERS; ++l) {
        const float* __restrict__ Wl  = cb + (size_t)l * KCB * DIM;
        const float* __restrict__ wql = wsq + l * KCB;
        const char*  Fb = (const char*)F + (size_t)l * 2097152;

        // ---- per-row ||r||^2: sum over aq in-wave, publish k-half partials ----
        float a0 = s2[0], a1 = s2[1];
        a0 += __shfl_xor(a0, 16); a0 += __shfl_xor(a0, 32);
        a1 += __shfl_xor(a1, 16); a1 += __shfl_xor(a1, 32);
        if (aq == 0) {
            rsqp[kt * 64 + rg * 32 + arow]      = a0;
            rsqp[kt * 64 + rg * 32 + 16 + arow] = a1;
        }
        __syncthreads();   // rsqp visible; chunk-0 staging drained (full drain OK here)

        float rsqC[2][4];
        #pragma unroll
        for (int mi = 0; mi < 2; ++mi)
            #pragma unroll
            for (int i = 0; i < 4; ++i) {
                int row = rg * 32 + mi * 16 + aq * 4 + i;
                rsqC[mi][i] = rsqp[row] + rsqp[64 + row];
            }

        float bestV[2][4];
        int   bestI[2][4];
        #pragma unroll
        for (int mi = 0; mi < 2; ++mi)
            #pragma unroll
            for (int i = 0; i < 4; ++i) { bestV[mi][i] = INFINITY; bestI[mi][i] = 0; }

        // ---- 64 chunks of 32 cw (tiles 2c, 2c+1), 2 raw barriers per chunk ----
        for (int c = 0; c < 64; ++c) {
            const int cur = c & 1;
            if (c + 1 < 64) stage_chunk32(Fb, Bsh + (size_t)(1 - cur) * 32768, c + 1, t);
            const char* bb = Bsh + (size_t)cur * 32768;

            __builtin_amdgcn_s_setprio(1);
            // non-owned tile (ti = 1-kt): partials -> LDS
            {
                f32x4 pn[2];
                tile_partial_pl(bb + (size_t)(1 - kt) * 16384, ahi, alo, kt, lane, pn);
                char* xw = Xch + rg * 4096 + kt * 2048;
                *(f32x4*)(xw + lane * 16)        = pn[0];
                *(f32x4*)(xw + 1024 + lane * 16) = pn[1];
            }
            // owned tile (ti = kt): keep partials in regs
            f32x4 po[2];
            tile_partial_pl(bb + (size_t)kt * 16384, ahi, alo, kt, lane, po);
            __builtin_amdgcn_s_setprio(0);

            // barrier A: Xch writes + all our B-fragment reads complete.
            // NO vmcnt drain: next-chunk staging stays in flight (T4).
            asm volatile("s_waitcnt lgkmcnt(0)" ::: "memory");
            __builtin_amdgcn_sched_barrier(0);
            __builtin_amdgcn_s_barrier();

            const char* xr = Xch + rg * 4096 + (1 - kt) * 2048;
            f32x4 pp0 = *(const f32x4*)(xr + lane * 16);
            f32x4 pp1 = *(const f32x4*)(xr + 1024 + lane * 16);

            const int col = c * 32 + kt * 16 + arow;
            const float wq = wql[col];
            #pragma unroll
            for (int i = 0; i < 4; ++i) {
                float c0 = po[0][i] + pp0[i];
                float d0 = (rsqC[0][i] - 2.f * c0) + wq;
                if (d0 < bestV[0][i]) { bestV[0][i] = d0; bestI[0][i] = col; }
                float c1 = po[1][i] + pp1[i];
                float d1 = (rsqC[1][i] - 2.f * c1) + wq;
                if (d1 < bestV[1][i]) { bestV[1][i] = d1; bestI[1][i] = col; }
            }

            // barrier B: Xch reads done (lgkm) AND next-chunk staging landed
            // (vmcnt(0) -- had a whole chunk to complete, ~free now).
            asm volatile("s_waitcnt vmcnt(0) lgkmcnt(0)" ::: "memory");
            __builtin_amdgcn_sched_barrier(0);
            __builtin_amdgcn_s_barrier();
        }

        // ---- argmin: reduce across the 16 arow-lanes sharing each row-quad ----
        #pragma unroll
        for (int mi = 0; mi < 2; ++mi)
            #pragma unroll
            for (int i = 0; i < 4; ++i) {
                float bv = bestV[mi][i]; int bi = bestI[mi][i];
                #pragma unroll
                for (int s = 8; s; s >>= 1) {
                    float ov = __shfl_xor(bv, s, 16);
                    int   oi = __shfl_xor(bi, s, 16);
                    if (ov < bv || (ov == bv && oi < bi)) { bv = ov; bi = oi; }
                }
                bestV[mi][i] = bv; bestI[mi][i] = bi;
            }
        if (arow == 0) {
            #pragma unroll
            for (int mi = 0; mi < 2; ++mi)
                #pragma unroll
                for (int i = 0; i < 4; ++i) {
                    bV_sh[wv * 32 + mi * 16 + aq * 4 + i] = bestV[mi][i];
                    bI_sh[wv * 32 + mi * 16 + aq * 4 + i] = bestI[mi][i];
                }
        }
        __syncthreads();

        // ---- combine the two k-teams' col-halves per row, write index ----
        if (t < 64) {
            int rgi = t >> 5, rl = t & 31;
            float v0 = bV_sh[(rgi * 2 + 0) * 32 + rl]; int i0 = bI_sh[(rgi * 2 + 0) * 32 + rl];
            float v1 = bV_sh[(rgi * 2 + 1) * 32 + rl]; int i1 = bI_sh[(rgi * 2 + 1) * 32 + rl];
            int bi = (v1 < v0 || (v1 == v0 && i1 < i0)) ? i1 : i0;
            bidx_sh[t] = bi;
            out[NQ + (size_t)l * NROWS + rowB + t] = (float)bi;
        }
        // prefetch next layer's chunk 0 (independent of bidx) into buf 0
        if (l < NUM_LAYERS - 1)
            stage_chunk32(Fb + 2097152, Bsh, 0, t);
        __syncthreads();   // bidx_sh visible

        if (l < NUM_LAYERS - 1) {
            // ---- residual update in registers: r <- (hi+lo) - w, re-split ----
            #pragma unroll
            for (int mi = 0; mi < 2; ++mi) {
                const int bi = bidx_sh[rg * 32 + mi * 16 + arow];
                const float* wrow = Wl + (size_t)bi * DIM;
                float ns = 0.f;
                #pragma unroll
                for (int kq = 0; kq < 4; ++kq) {
                    const float* wp = wrow + (kt * 4 + kq) * 32 + aq * 8;
                    float4 w0 = *(const float4*)(wp);
                    float4 w1 = *(const float4*)(wp + 4);
                    float wv8[8] = {w0.x, w0.y, w0.z, w0.w, w1.x, w1.y, w1.z, w1.w};
                    #pragma unroll
                    for (int j = 0; j < 8; ++j) {
                        float r = ((float)ahi[mi][kq][j] + (float)alo[mi][kq][j]) - wv8[j];
                        _Float16 hv = (_Float16)r;
                        ahi[mi][kq][j] = hv;
                        alo[mi][kq][j] = (_Float16)(r - (float)hv);
                        ns = fmaf(r, r, ns);
                    }
                }
                s2[mi] = ns;
            }
        } else {
            // ---- final: out = h - (r2 - w3); each lane covers its k-half ----
            #pragma unroll
            for (int mi = 0; mi < 2; ++mi) {
                const int row = row0w + mi * 16 + arow;
                const int bi  = bidx_sh[rg * 32 + mi * 16 + arow];
                const float* wrow = Wl + (size_t)bi * DIM;
                #pragma unroll
                for (int kq = 0; kq < 4; ++kq) {
                    const int ko = (kt * 4 + kq) * 32 + aq * 8;
                    const float* wp = wrow + ko;
                    const float* hp = h + (size_t)row * DIM + ko;
                    float4 w0 = *(const float4*)(wp);
                    float4 w1 = *(const float4*)(wp + 4);
                    float4 h0 = *(const float4*)(hp);
                    float4 h1 = *(const float4*)(hp + 4);
                    float wv8[8] = {w0.x, w0.y, w0.z, w0.w, w1.x, w1.y, w1.z, w1.w};
                    float hv8[8] = {h0.x, h0.y, h0.z, h0.w, h1.x, h1.y, h1.z, h1.w};
                    float o[8];
                    #pragma unroll
                    for (int j = 0; j < 8; ++j) {
                        float r = ((float)ahi[mi][kq][j] + (float)alo[mi][kq][j]) - wv8[j];
                        o[j] = hv8[j] - r;
                    }
                    float* op = out + (size_t)row * DIM + ko;
                    *(float4*)(op)     = make_float4(o[0], o[1], o[2], o[3]);
                    *(float4*)(op + 4) = make_float4(o[4], o[5], o[6], o[7]);
                }
            }
        }
    }
}

extern "C" void kernel_launch(void* const* d_in, const int* in_sizes, int n_in,
                              void* d_out, int out_size, void* d_ws, size_t ws_size,
                              hipStream_t stream) {
    const float* h  = (const float*)d_in[0];
    const float* cb = (const float*)d_in[1];
    float* out = (float*)d_out;
    unsigned short* F = (unsigned short*)d_ws;
    float* wsq = (float*)((char*)d_ws + F_BYTES);

    hipFuncSetAttribute((const void*)rvq_main,
                        hipFuncAttributeMaxDynamicSharedMemorySize, SMEM_BYTES);

    rvq_wsq   <<<dim3(24),   dim3(256), 0, stream>>>(cb, wsq);
    rvq_repack<<<dim3(3072), dim3(64),  0, stream>>>(cb, F);
    rvq_main  <<<dim3(NROWS / 64), dim3(256), SMEM_BYTES, stream>>>(h, cb, F, wsq, out);
}

// Round 5
// 386.291 us; speedup vs baseline: 1.0858x; 1.0326x over previous
//
#include <hip/hip_runtime.h>
#include <math.h>

#define NUM_LAYERS 3
#define KCB 2048        // codebook size
#define DIM 256         // embed dim
#define NROWS 32768     // B*T
#define NQ (NROWS * DIM)

// d_ws layout: F = fp16 codebook fragments (16x16x32 layout, verified).
//   tile tn (16 cw) = 16384 B = 8 kb-blocks of [hi 1024 B | lo 1024 B]
//   within a 1024 B half: lane*16 B -> 8 halves: W[tn*16+(lane&15)][kb*32+(lane>>4)*8+j]
//   layer stride 2 MB. wsq (fp32 ||w||^2, 3*2048) at byte offset F_BYTES.
//   chunk c = 32 KB = tiles {2c, 2c+1} at Fb + c*32768.
#define F_BYTES (3u * 128u * 16384u)   // 6,291,456

// dynamic LDS partition (bytes) -- one 512-thr block per CU
#define BSH_OFF  0        // 2 bufs x 32768 (one 32-cw chunk each)
#define XCH_OFF  65536    // 2 bufs x [rg 0..3][kt 0..1] x 2048 B = 2 x 16384
#define RSQP_OFF 98304    // [kt 0..1][128 rows] f32 = 1024
#define BV_OFF   99328    // 8 waves x 32 rows f32 = 1024
#define BI_OFF   100352   // 8 x 32 i32 = 1024
#define BIDX_OFF 101376   // 128 i32 = 512
#define SMEM_BYTES 101888

typedef _Float16 half8 __attribute__((ext_vector_type(8)));
typedef float   f32x4 __attribute__((ext_vector_type(4)));

// ---------------- prep: ||w||^2 (unchanged, verified) ----------------
__global__ void rvq_wsq(const float* __restrict__ cb, float* __restrict__ wsq)
{
    int tid = blockIdx.x * 256 + threadIdx.x;   // 0 .. 6143
    const float* p = cb + (size_t)tid * DIM;
    float s = 0.f;
    #pragma unroll
    for (int u = 0; u < 64; ++u) {
        float4 v = *(const float4*)(p + u * 4);
        s = fmaf(v.x, v.x, s); s = fmaf(v.y, v.y, s);
        s = fmaf(v.z, v.z, s); s = fmaf(v.w, v.w, s);
    }
    wsq[tid] = s;
}

// ---------------- prep: fp16 hi/lo fragment repack (unchanged, verified) ----------------
__global__ void rvq_repack(const float* __restrict__ cb, unsigned short* __restrict__ F)
{
    int b = blockIdx.x;           // layer*1024 + tn*8 + kb
    int layer = b >> 10;
    int rem   = b & 1023;
    int tn    = rem >> 3;
    int kb    = rem & 7;
    int lane  = threadIdx.x;

    int cw = tn * 16 + (lane & 15);
    int k0 = kb * 32 + (lane >> 4) * 8;
    const float* src = cb + ((size_t)(layer * KCB + cw)) * DIM + k0;
    float4 x0 = *(const float4*)(src);
    float4 x1 = *(const float4*)(src + 4);
    float v[8] = {x0.x, x0.y, x0.z, x0.w, x1.x, x1.y, x1.z, x1.w};

    half8 hi, lo;
    #pragma unroll
    for (int j = 0; j < 8; ++j) {
        _Float16 h = (_Float16)v[j];
        hi[j] = h;
        lo[j] = (_Float16)(v[j] - (float)h);
    }
    size_t base = ((size_t)b) * 1024;   // ushort units (2048 B per (layer,tn,kb))
    *(half8*)(F + base + lane * 8)        = hi;
    *(half8*)(F + base + 512 + lane * 8)  = lo;
}

// ---------------- async stage of one 32 KB chunk (512 threads) ----------------
__device__ __forceinline__ void stage_chunk32(const char* Fb, char* dst, int c, int t)
{
    const char* g = Fb + (size_t)c * 32768;
    #pragma unroll
    for (int i = 0; i < 4; ++i) {
        int off = (i * 512 + t) * 16;
        __builtin_amdgcn_global_load_lds(
            (const __attribute__((address_space(1))) unsigned int*)(g + off),
            (__attribute__((address_space(3))) unsigned int*)(dst + off), 16, 0, 0);
    }
}

// ---------------- pipelined partial cross: 16-cw tile over this wave's k-half ----------------
// 1-step register prefetch + sched_group_barrier pins ({DS_READ x2, MFMA x6})
// so the emitted schedule interleaves the LDS pipe with the matrix pipe.
__device__ __forceinline__ void tile_partial_pl(
    const char* tbase, const half8 (&ahi)[2][4], const half8 (&alo)[2][4],
    int kt, int lane, f32x4 (&po)[2])
{
    const f32x4 z = {0.f, 0.f, 0.f, 0.f};
    f32x4 a00 = z, a01 = z, a10 = z, a11 = z;
    const char* p = tbase + kt * 4 * 2048 + lane * 16;
    half8 bhi = *(const half8*)(p);
    half8 blo = *(const half8*)(p + 1024);
    #pragma unroll
    for (int kq = 0; kq < 4; ++kq) {
        half8 nhi, nlo;
        if (kq < 3) {
            nhi = *(const half8*)(p + (kq + 1) * 2048);
            nlo = *(const half8*)(p + (kq + 1) * 2048 + 1024);
            __builtin_amdgcn_sched_group_barrier(0x100, 2, 0);   // 2 DS_READ
        }
        if (kq & 1) {
            a01 = __builtin_amdgcn_mfma_f32_16x16x32_f16(ahi[0][kq], bhi, a01, 0, 0, 0);
            a11 = __builtin_amdgcn_mfma_f32_16x16x32_f16(ahi[1][kq], bhi, a11, 0, 0, 0);
            a01 = __builtin_amdgcn_mfma_f32_16x16x32_f16(alo[0][kq], bhi, a01, 0, 0, 0);
            a11 = __builtin_amdgcn_mfma_f32_16x16x32_f16(alo[1][kq], bhi, a11, 0, 0, 0);
            a01 = __builtin_amdgcn_mfma_f32_16x16x32_f16(ahi[0][kq], blo, a01, 0, 0, 0);
            a11 = __builtin_amdgcn_mfma_f32_16x16x32_f16(ahi[1][kq], blo, a11, 0, 0, 0);
        } else {
            a00 = __builtin_amdgcn_mfma_f32_16x16x32_f16(ahi[0][kq], bhi, a00, 0, 0, 0);
            a10 = __builtin_amdgcn_mfma_f32_16x16x32_f16(ahi[1][kq], bhi, a10, 0, 0, 0);
            a00 = __builtin_amdgcn_mfma_f32_16x16x32_f16(alo[0][kq], bhi, a00, 0, 0, 0);
            a10 = __builtin_amdgcn_mfma_f32_16x16x32_f16(alo[1][kq], bhi, a10, 0, 0, 0);
            a00 = __builtin_amdgcn_mfma_f32_16x16x32_f16(ahi[0][kq], blo, a00, 0, 0, 0);
            a10 = __builtin_amdgcn_mfma_f32_16x16x32_f16(ahi[1][kq], blo, a10, 0, 0, 0);
        }
        __builtin_amdgcn_sched_group_barrier(0x8, 6, 0);         // 6 MFMA
        if (kq < 3) { bhi = nhi; blo = nlo; }
    }
    #pragma unroll
    for (int i = 0; i < 4; ++i) { po[0][i] = a00[i] + a01[i]; po[1][i] = a10[i] + a11[i]; }
}

// ---------------- main fused RVQ ----------------
// 512 thr = 8 waves: wave = rg(0..3)*2 + kt(0..1). 128 rows/block, grid 256,
// 1 block/CU. k-half fragments (64 VGPRs, proven no-spill footprint).
// DEFERRED EXCHANGE (R5): partials for chunk c are written to Xch[c&1] and
// consumed during chunk c+1's MFMA phase -> ONE barrier per chunk, no
// mid-chunk lgkm stall; the Xch read + combine VALU hide under next chunk's
// MFMAs. po (own-tile partials) carried in regs across one chunk (8 VGPRs).
__global__ __launch_bounds__(512, 2)
void rvq_main(const float* __restrict__ h,
              const float* __restrict__ cb,
              const unsigned short* __restrict__ F,
              const float* __restrict__ wsq,
              float* __restrict__ out)
{
    extern __shared__ char smem[];
    char*  Bsh     = smem + BSH_OFF;
    char*  Xch     = smem + XCH_OFF;
    float* rsqp    = (float*)(smem + RSQP_OFF);
    float* bV_sh   = (float*)(smem + BV_OFF);
    int*   bI_sh   = (int*)  (smem + BI_OFF);
    int*   bidx_sh = (int*)  (smem + BIDX_OFF);

    const int t     = threadIdx.x;
    const int lane  = t & 63;
    const int wv    = t >> 6;         // 0..7
    const int kt    = wv & 1;         // k-team: k in [kt*128, kt*128+128)
    const int rg    = wv >> 1;        // row group (32 rows each)
    const int rowB  = blockIdx.x * 128;
    const int row0w = rowB + rg * 32;
    const int arow  = lane & 15;      // A row / C col
    const int aq    = lane >> 4;      // k-quad / C row-quad

    // ---- residual fragments (fp16 hi/lo, k-half only) + partial ||r||^2 ----
    half8 ahi[2][4], alo[2][4];
    float s2[2];
    #pragma unroll
    for (int mi = 0; mi < 2; ++mi) {
        s2[mi] = 0.f;
        #pragma unroll
        for (int kq = 0; kq < 4; ++kq) {
            const float* p = h + (size_t)(row0w + mi * 16 + arow) * DIM + (kt * 4 + kq) * 32 + aq * 8;
            float4 x0 = *(const float4*)(p);
            float4 x1 = *(const float4*)(p + 4);
            float v[8] = {x0.x, x0.y, x0.z, x0.w, x1.x, x1.y, x1.z, x1.w};
            #pragma unroll
            for (int j = 0; j < 8; ++j) {
                _Float16 hv = (_Float16)v[j];
                ahi[mi][kq][j] = hv;
                alo[mi][kq][j] = (_Float16)(v[j] - (float)hv);
                s2[mi] = fmaf(v[j], v[j], s2[mi]);
            }
        }
    }

    // ---- prefetch layer 0, chunk 0 into buf 0 ----
    stage_chunk32((const char*)F, Bsh, 0, t);

    for (int l = 0; l < NUM_LAYERS; ++l) {
        const float* __restrict__ Wl  = cb + (size_t)l * KCB * DIM;
        const float* __restrict__ wql = wsq + l * KCB;
        const char*  Fb = (const char*)F + (size_t)l * 2097152;

        // ---- per-row ||r||^2: sum over aq in-wave, publish k-half partials ----
        float a0 = s2[0], a1 = s2[1];
        a0 += __shfl_xor(a0, 16); a0 += __shfl_xor(a0, 32);
        a1 += __shfl_xor(a1, 16); a1 += __shfl_xor(a1, 32);
        if (aq == 0) {
            rsqp[kt * 128 + rg * 32 + arow]      = a0;
            rsqp[kt * 128 + rg * 32 + 16 + arow] = a1;
        }
        __syncthreads();   // rsqp visible; chunk-0 staging drained (full drain, once/layer)

        float rsqC[2][4];
        #pragma unroll
        for (int mi = 0; mi < 2; ++mi)
            #pragma unroll
            for (int i = 0; i < 4; ++i) {
                int row = rg * 32 + mi * 16 + aq * 4 + i;
                rsqC[mi][i] = rsqp[row] + rsqp[128 + row];
            }

        float bestV[2][4];
        int   bestI[2][4];
        #pragma unroll
        for (int mi = 0; mi < 2; ++mi)
            #pragma unroll
            for (int i = 0; i < 4; ++i) { bestV[mi][i] = INFINITY; bestI[mi][i] = 0; }

        f32x4 po_prev[2];

        // ---- chunk 0 (prime the exchange pipeline) ----
        {
            stage_chunk32(Fb, Bsh + 32768, 1, t);
            const char* bb = Bsh;
            __builtin_amdgcn_s_setprio(1);
            {
                f32x4 pn[2];
                tile_partial_pl(bb + (size_t)(1 - kt) * 16384, ahi, alo, kt, lane, pn);
                char* xw = Xch + rg * 4096 + kt * 2048;          // buf 0
                *(f32x4*)(xw + lane * 16)        = pn[0];
                *(f32x4*)(xw + 1024 + lane * 16) = pn[1];
            }
            tile_partial_pl(bb + (size_t)kt * 16384, ahi, alo, kt, lane, po_prev);
            __builtin_amdgcn_s_setprio(0);
            asm volatile("s_waitcnt vmcnt(0) lgkmcnt(0)" ::: "memory");
            __builtin_amdgcn_sched_barrier(0);
            __builtin_amdgcn_s_barrier();
        }

        // ---- chunks 1..63: consume partner partials for c-1, produce for c ----
        for (int c = 1; c < 64; ++c) {
            const int cur = c & 1;
            if (c + 1 < 64) stage_chunk32(Fb, Bsh + (size_t)(1 - cur) * 32768, c + 1, t);
            const char* bb = Bsh + (size_t)cur * 32768;

            // partner partials for chunk c-1 (written a chunk ago, post-barrier)
            const char* xr = Xch + (size_t)(1 - cur) * 16384 + rg * 4096 + (1 - kt) * 2048;
            f32x4 pp0 = *(const f32x4*)(xr + lane * 16);
            f32x4 pp1 = *(const f32x4*)(xr + 1024 + lane * 16);

            __builtin_amdgcn_s_setprio(1);
            f32x4 pn[2];
            tile_partial_pl(bb + (size_t)(1 - kt) * 16384, ahi, alo, kt, lane, pn);
            __builtin_amdgcn_s_setprio(0);

            // combine + argmin for chunk c-1 (VALU; overlaps other waves' MFMAs)
            {
                const int col = (c - 1) * 32 + kt * 16 + arow;
                const float wq = wql[col];
                #pragma unroll
                for (int i = 0; i < 4; ++i) {
                    float c0 = po_prev[0][i] + pp0[i];
                    float d0 = (rsqC[0][i] - 2.f * c0) + wq;
                    if (d0 < bestV[0][i]) { bestV[0][i] = d0; bestI[0][i] = col; }
                    float c1 = po_prev[1][i] + pp1[i];
                    float d1 = (rsqC[1][i] - 2.f * c1) + wq;
                    if (d1 < bestV[1][i]) { bestV[1][i] = d1; bestI[1][i] = col; }
                }
            }

            // ship chunk-c non-owned partials
            {
                char* xw = Xch + (size_t)cur * 16384 + rg * 4096 + kt * 2048;
                *(f32x4*)(xw + lane * 16)        = pn[0];
                *(f32x4*)(xw + 1024 + lane * 16) = pn[1];
            }

            __builtin_amdgcn_s_setprio(1);
            tile_partial_pl(bb + (size_t)kt * 16384, ahi, alo, kt, lane, po_prev);
            __builtin_amdgcn_s_setprio(0);

            // single barrier: our Xch write + B-reads done (lgkm); staging for
            // c+1 landed (vmcnt -- issued a full chunk ago, ~free).
            asm volatile("s_waitcnt vmcnt(0) lgkmcnt(0)" ::: "memory");
            __builtin_amdgcn_sched_barrier(0);
            __builtin_amdgcn_s_barrier();
        }

        // ---- epilogue: combine chunk 63 ----
        {
            const char* xr = Xch + 16384 + rg * 4096 + (1 - kt) * 2048;  // buf 1 (63&1)
            f32x4 pp0 = *(const f32x4*)(xr + lane * 16);
            f32x4 pp1 = *(const f32x4*)(xr + 1024 + lane * 16);
            const int col = 63 * 32 + kt * 16 + arow;
            const float wq = wql[col];
            #pragma unroll
            for (int i = 0; i < 4; ++i) {
                float c0 = po_prev[0][i] + pp0[i];
                float d0 = (rsqC[0][i] - 2.f * c0) + wq;
                if (d0 < bestV[0][i]) { bestV[0][i] = d0; bestI[0][i] = col; }
                float c1 = po_prev[1][i] + pp1[i];
                float d1 = (rsqC[1][i] - 2.f * c1) + wq;
                if (d1 < bestV[1][i]) { bestV[1][i] = d1; bestI[1][i] = col; }
            }
        }

        // ---- argmin: reduce across the 16 arow-lanes sharing each row-quad ----
        #pragma unroll
        for (int mi = 0; mi < 2; ++mi)
            #pragma unroll
            for (int i = 0; i < 4; ++i) {
                float bv = bestV[mi][i]; int bi = bestI[mi][i];
                #pragma unroll
                for (int s = 8; s; s >>= 1) {
                    float ov = __shfl_xor(bv, s, 16);
                    int   oi = __shfl_xor(bi, s, 16);
                    if (ov < bv || (ov == bv && oi < bi)) { bv = ov; bi = oi; }
                }
                bestV[mi][i] = bv; bestI[mi][i] = bi;
            }
        if (arow == 0) {
            #pragma unroll
            for (int mi = 0; mi < 2; ++mi)
                #pragma unroll
                for (int i = 0; i < 4; ++i) {
                    bV_sh[wv * 32 + mi * 16 + aq * 4 + i] = bestV[mi][i];
                    bI_sh[wv * 32 + mi * 16 + aq * 4 + i] = bestI[mi][i];
                }
        }
        __syncthreads();

        // ---- combine the two k-teams' col-halves per row, write index ----
        if (t < 128) {
            int rgi = t >> 5, rl = t & 31;
            float v0 = bV_sh[(rgi * 2 + 0) * 32 + rl]; int i0 = bI_sh[(rgi * 2 + 0) * 32 + rl];
            float v1 = bV_sh[(rgi * 2 + 1) * 32 + rl]; int i1 = bI_sh[(rgi * 2 + 1) * 32 + rl];
            int bi = (v1 < v0 || (v1 == v0 && i1 < i0)) ? i1 : i0;
            bidx_sh[t] = bi;
            out[NQ + (size_t)l * NROWS + rowB + t] = (float)bi;
        }
        // prefetch next layer's chunk 0 (independent of bidx) into buf 0
        if (l < NUM_LAYERS - 1)
            stage_chunk32(Fb + 2097152, Bsh, 0, t);
        __syncthreads();   // bidx_sh visible

        if (l < NUM_LAYERS - 1) {
            // ---- residual update in registers: r <- (hi+lo) - w, re-split ----
            #pragma unroll
            for (int mi = 0; mi < 2; ++mi) {
                const int bi = bidx_sh[rg * 32 + mi * 16 + arow];
                const float* wrow = Wl + (size_t)bi * DIM;
                float ns = 0.f;
                #pragma unroll
                for (int kq = 0; kq < 4; ++kq) {
                    const float* wp = wrow + (kt * 4 + kq) * 32 + aq * 8;
                    float4 w0 = *(const float4*)(wp);
                    float4 w1 = *(const float4*)(wp + 4);
                    float wv8[8] = {w0.x, w0.y, w0.z, w0.w, w1.x, w1.y, w1.z, w1.w};
                    #pragma unroll
                    for (int j = 0; j < 8; ++j) {
                        float r = ((float)ahi[mi][kq][j] + (float)alo[mi][kq][j]) - wv8[j];
                        _Float16 hv = (_Float16)r;
                        ahi[mi][kq][j] = hv;
                        alo[mi][kq][j] = (_Float16)(r - (float)hv);
                        ns = fmaf(r, r, ns);
                    }
                }
                s2[mi] = ns;
            }
        } else {
            // ---- final: out = h - (r2 - w3); each lane covers its k-half ----
            #pragma unroll
            for (int mi = 0; mi < 2; ++mi) {
                const int row = row0w + mi * 16 + arow;
                const int bi  = bidx_sh[rg * 32 + mi * 16 + arow];
                const float* wrow = Wl + (size_t)bi * DIM;
                #pragma unroll
                for (int kq = 0; kq < 4; ++kq) {
                    const int ko = (kt * 4 + kq) * 32 + aq * 8;
                    const float* wp = wrow + ko;
                    const float* hp = h + (size_t)row * DIM + ko;
                    float4 w0 = *(const float4*)(wp);
                    float4 w1 = *(const float4*)(wp + 4);
                    float4 h0 = *(const float4*)(hp);
                    float4 h1 = *(const float4*)(hp + 4);
                    float wv8[8] = {w0.x, w0.y, w0.z, w0.w, w1.x, w1.y, w1.z, w1.w};
                    float hv8[8] = {h0.x, h0.y, h0.z, h0.w, h1.x, h1.y, h1.z, h1.w};
                    float o[8];
                    #pragma unroll
                    for (int j = 0; j < 8; ++j) {
                        float r = ((float)ahi[mi][kq][j] + (float)alo[mi][kq][j]) - wv8[j];
                        o[j] = hv8[j] - r;
                    }
                    float* op = out + (size_t)row * DIM + ko;
                    *(float4*)(op)     = make_float4(o[0], o[1], o[2], o[3]);
                    *(float4*)(op + 4) = make_float4(o[4], o[5], o[6], o[7]);
                }
            }
        }
    }
}

extern "C" void kernel_launch(void* const* d_in, const int* in_sizes, int n_in,
                              void* d_out, int out_size, void* d_ws, size_t ws_size,
                              hipStream_t stream) {
    const float* h  = (const float*)d_in[0];
    const float* cb = (const float*)d_in[1];
    float* out = (float*)d_out;
    unsigned short* F = (unsigned short*)d_ws;
    float* wsq = (float*)((char*)d_ws + F_BYTES);

    hipFuncSetAttribute((const void*)rvq_main,
                        hipFuncAttributeMaxDynamicSharedMemorySize, SMEM_BYTES);

    rvq_wsq   <<<dim3(24),   dim3(256), 0, stream>>>(cb, wsq);
    rvq_repack<<<dim3(3072), dim3(64),  0, stream>>>(cb, F);
    rvq_main  <<<dim3(NROWS / 128), dim3(512), SMEM_BYTES, stream>>>(h, cb, F, wsq, out);
}